// Round 2
// baseline (112.919 us; speedup 1.0000x reference)
//
#include <hip/hip_runtime.h>
#include <hip/hip_bf16.h>

namespace {
constexpr int B   = 16;
constexpr int NS  = 1000;
constexpr int IN  = 128;
constexpr int OUT = 128;
constexpr int K   = 256;  // IN + OUT

__device__ __forceinline__ float fsigmoid(float x) {
  return 1.0f / (1.0f + __expf(-x));
}
__device__ __forceinline__ float ftanh(float x) {
  return 2.0f / (1.0f + __expf(-2.0f * x)) - 1.0f;
}

__global__ __launch_bounds__(256, 4) void lstm_kernel(
    const float* __restrict__ xt, const float* __restrict__ hidden,
    const float* __restrict__ ct_1,
    const float* __restrict__ Wi, const float* __restrict__ bi,
    const float* __restrict__ Wo, const float* __restrict__ bo,
    const float* __restrict__ Wf, const float* __restrict__ bfp,
    const float* __restrict__ Wc, const float* __restrict__ bc,
    float* __restrict__ out) {
  // Phase 1 view: xh[16][256] fp32 (16 KiB). Phase 2 view: gbuf[4][16][128] (32 KiB).
  __shared__ float smem[4 * B * OUT];
  float (*xh)[K] = (float (*)[K])smem;

  const int n = blockIdx.x;
  const int tid = threadIdx.x;

  // ---- stage xh = concat(xt[:, n, :], hidden[0, n, :]) into LDS ----
  #pragma unroll
  for (int r = 0; r < 2; ++r) {
    const int idx = tid + (r << 8);   // 0..511
    const int b = idx >> 5;           // 0..15
    const int j = (idx & 31) << 2;    // 0,4,...,124
    const float4 xv = *reinterpret_cast<const float4*>(
        xt + ((size_t)b * NS + n) * IN + j);
    *reinterpret_cast<float4*>(&xh[b][j]) = xv;
    const float4 hv = *reinterpret_cast<const float4*>(
        hidden + (size_t)n * OUT + j);
    *reinterpret_cast<float4*>(&xh[b][IN + j]) = hv;
  }
  __syncthreads();

  const int g  = tid >> 6;   // gate 0..3 (wave-uniform: one gate per wave)
  const int ol = tid & 63;   // owns columns ol and ol+64

  const float* Wg = (g == 0) ? Wi : (g == 1) ? Wo : (g == 2) ? Wf : Wc;
  const float* bg = (g == 0) ? bi : (g == 1) ? bo : (g == 2) ? bfp : bc;
  const float* wp = Wg + (size_t)n * (K * OUT) + ol;

  float acc0[B], acc1[B];
  #pragma unroll
  for (int b = 0; b < B; ++b) { acc0[b] = 0.f; acc1[b] = 0.f; }

  #pragma unroll 2
  for (int k = 0; k < K; k += 4) {
    float w0[4], w1[4];
    #pragma unroll
    for (int q = 0; q < 4; ++q) {
      w0[q] = wp[(size_t)(k + q) * OUT];
      w1[q] = wp[(size_t)(k + q) * OUT + 64];
    }
    #pragma unroll
    for (int b = 0; b < B; ++b) {
      const float4 x = *reinterpret_cast<const float4*>(&xh[b][k]);  // LDS broadcast
      acc0[b] = fmaf(x.x, w0[0], acc0[b]);
      acc0[b] = fmaf(x.y, w0[1], acc0[b]);
      acc0[b] = fmaf(x.z, w0[2], acc0[b]);
      acc0[b] = fmaf(x.w, w0[3], acc0[b]);
      acc1[b] = fmaf(x.x, w1[0], acc1[b]);
      acc1[b] = fmaf(x.y, w1[1], acc1[b]);
      acc1[b] = fmaf(x.z, w1[2], acc1[b]);
      acc1[b] = fmaf(x.w, w1[3], acc1[b]);
    }
  }

  const float bias0 = bg[(size_t)n * OUT + ol];
  const float bias1 = bg[(size_t)n * OUT + ol + 64];

  __syncthreads();  // all xh reads done; safe to repurpose smem as gbuf
  #pragma unroll
  for (int b = 0; b < B; ++b) {
    smem[((g * B + b) << 7) + ol]      = acc0[b] + bias0;
    smem[((g * B + b) << 7) + ol + 64] = acc1[b] + bias1;
  }
  __syncthreads();

  // ---- combine gates, write ht and ct (fp32 outputs) ----
  const size_t nbase = (size_t)n * OUT;
  #pragma unroll
  for (int r = 0; r < 8; ++r) {
    const int p = tid + (r << 8);  // 0..2047
    const int b = p >> 7;
    const int o = p & 127;
    const float gi = smem[((0 * B + b) << 7) + o];
    const float go = smem[((1 * B + b) << 7) + o];
    const float gf = smem[((2 * B + b) << 7) + o];
    const float gc = smem[((3 * B + b) << 7) + o];
    const float it = fsigmoid(gi);
    const float ot = fsigmoid(go);
    const float ft = fsigmoid(gf);
    const float ch = ftanh(gc);
    const float cp = ct_1[nbase + o];
    const float ct = ft * cp + it * ch;
    const float ht = ot * ftanh(ct);
    const size_t oidx = (size_t)b * ((size_t)NS * OUT) + nbase + o;
    out[oidx] = ht;                              // ht
    out[(size_t)B * NS * OUT + oidx] = ct;       // ct
  }
}
}  // namespace

extern "C" void kernel_launch(void* const* d_in, const int* in_sizes, int n_in,
                              void* d_out, int out_size, void* d_ws, size_t ws_size,
                              hipStream_t stream) {
  const float* xt     = (const float*)d_in[0];
  const float* hidden = (const float*)d_in[1];
  const float* ct_1   = (const float*)d_in[2];
  const float* Wi     = (const float*)d_in[3];
  const float* bi     = (const float*)d_in[4];
  const float* Wo     = (const float*)d_in[5];
  const float* bo     = (const float*)d_in[6];
  const float* Wf     = (const float*)d_in[7];
  const float* bf     = (const float*)d_in[8];
  const float* Wc     = (const float*)d_in[9];
  const float* bc     = (const float*)d_in[10];

  lstm_kernel<<<NS, 256, 0, stream>>>(xt, hidden, ct_1, Wi, bi, Wo, bo,
                                      Wf, bf, Wc, bc,
                                      (float*)d_out);
}